// Round 4
// baseline (140.157 us; speedup 1.0000x reference)
//
#include <hip/hip_runtime.h>
#include <hip/hip_bf16.h>
#include <math.h>

#define Bn 4
#define Nn 512
#define Dn 128
#define Hn 64
#define TT 4096                  // table resolution (nearest-neighbor lookup)
#define EPB 8
#define K0B ((TT + 1 + EPB - 1) / EPB)
#define NTAB_BF_OFF (1 << 21)    // byte offset of bf16 ntab copy in workspace

__device__ __forceinline__ float silu_f(float x) {
    return x * (1.0f / (1.0f + __expf(-x)));
}

// ---------------------------------------------------------------------------
// k0: tabulate radial MLP G(x): scalar -> R^128 at x = e/TT.
// R16 = R15 (LDS h-buf broadcast form, wave-private so no inner barriers)
// + 25 of the 513 blocks additionally convert ntab fp32 -> bf16 into the
// workspace (bit-identical __float2bfloat16; consumed by k1's gathers).
// ---------------------------------------------------------------------------
struct K0S {
    float rW2s[Hn][Hn];
    float rW3s[Hn][Dn];
    float rW1s[Hn], rb1s[Hn], rg1s[Hn], rb2s[Hn], rg2s[Hn];
    float rb3s[Dn];
    float h1buf[4][Hn];
    float h2buf[4][Hn];
};

__global__ __launch_bounds__(256)
void k0_build_table(const float* __restrict__ rW1, const float* __restrict__ rb1,
                    const float* __restrict__ rg1,
                    const float* __restrict__ rW2, const float* __restrict__ rb2,
                    const float* __restrict__ rg2,
                    const float* __restrict__ rW3, const float* __restrict__ rb3,
                    const float* __restrict__ ntab,
                    __hip_bfloat162* __restrict__ ntab_bf,
                    __hip_bfloat16* __restrict__ table)
{
    __shared__ K0S sm;
    const int t  = threadIdx.x;
    const int k  = t & 63;
    const int wv = t >> 6;

    // bf16 ntab precompute: 100*128 floats = 6400 float2 = 25 blocks x 256 thr
    if (blockIdx.x < 25) {
        const int idx = blockIdx.x * 256 + t;
        const float2 fv = ((const float2*)ntab)[idx];
        ntab_bf[idx] = __hip_bfloat162(__float2bfloat16(fv.x), __float2bfloat16(fv.y));
    }

    #pragma unroll
    for (int idx = t; idx < Hn * Hn; idx += 256)
        sm.rW2s[idx >> 6][idx & 63] = rW2[idx];
    #pragma unroll
    for (int idx = t; idx < Hn * Dn; idx += 256)
        sm.rW3s[idx >> 7][idx & 127] = rW3[idx];
    if (t < Hn) {
        sm.rW1s[t] = rW1[t];
        sm.rb1s[t] = rb1[t];
        sm.rg1s[t] = rg1[t];
        sm.rb2s[t] = rb2[t];
        sm.rg2s[t] = rg2[t];
    }
    if (t < Dn) sm.rb3s[t] = rb3[t];
    __syncthreads();                      // only barrier in the kernel

    const float w1v = sm.rW1s[k], b1v = sm.rb1s[k], g1v = sm.rg1s[k];
    const float b2v = sm.rb2s[k], g2v = sm.rg2s[k];

    for (int r = 0; r < EPB / 4; ++r) {
        const int e = blockIdx.x * EPB + r * 4 + wv;
        const float x = (float)e * (1.0f / (float)TT);

        float h = silu_f(x * w1v + b1v);
        float s1 = h, s2 = h * h;
        #pragma unroll
        for (int m = 1; m < 64; m <<= 1) { s1 += __shfl_xor(s1, m); s2 += __shfl_xor(s2, m); }
        float mean = s1 * (1.0f / 64.0f);
        float var  = s2 * (1.0f / 64.0f) - mean * mean;
        float rs   = rsqrtf(var + 1e-5f);
        sm.h1buf[wv][k] = (h - mean) * rs * g1v;
        // wave-private buffer: same-wave DS ordering (lgkmcnt) suffices.

        float p = 0.f;
        #pragma unroll 8
        for (int kk = 0; kk < Hn; ++kk)
            p += sm.h1buf[wv][kk] * sm.rW2s[kk][k];
        float h2 = silu_f(p + b2v);
        s1 = h2; s2 = h2 * h2;
        #pragma unroll
        for (int m = 1; m < 64; m <<= 1) { s1 += __shfl_xor(s1, m); s2 += __shfl_xor(s2, m); }
        mean = s1 * (1.0f / 64.0f);
        var  = s2 * (1.0f / 64.0f) - mean * mean;
        rs   = rsqrtf(var + 1e-5f);
        sm.h2buf[wv][k] = (h2 - mean) * rs * g2v;

        #pragma unroll
        for (int dd = 0; dd < 2; ++dd) {
            const int d = dd * 64 + k;
            float f = sm.rb3s[d];
            #pragma unroll 8
            for (int kk = 0; kk < Hn; ++kk)
                f += sm.h2buf[wv][kk] * sm.rW3s[kk][d];
            if (e <= TT) table[e * Dn + d] = __float2bfloat16(f);
        }
    }
}

// ---------------------------------------------------------------------------
// k1: fully fused.  Block = 4 rows (512 blocks); wave = one full row.
// R16 vs R15:
//   - ntab LDS staging ELIMINATED: contraction gathers bf16 ntab directly
//     from global (25.6 KB, L1/L2-resident; precomputed by k0). Removes
//     ~26 MB of per-block staging reads + 12800 cvts per block.
//   - barrier B1 removed: ent is wave-private (same-wave DS ordering,
//     the pattern hardware-validated by R15's k0) -> each wave flows
//     compaction -> contraction with no block-wide sync.  5 barriers.
//   - LDS 47.0 -> 22.0 KB -> ~5-7 blocks/CU (was 3): latency hiding for
//     the gather-bound contraction and the compaction loads.
//   - contraction / epilogue arithmetic identical to R15 (bit-for-bit).
// ---------------------------------------------------------------------------
struct K1S {
    union {
        float2 ent[4][512];                // wave-private entry lists (16 KB)
        struct {
            float xs[4][256];              // 4 KB  [emb | nf] per row
            float pp[8][4][128];           // 16 KB GEMV partials [ch][row][out]
            float x2[4][128];              // 2 KB  post-LN/silu
        } epi;                             // 22 KB
    } u;
};

__global__ __launch_bounds__(256)
void k1_fused(const int* __restrict__ atoms, const float* __restrict__ rel,
              const int* __restrict__ adj, const int* __restrict__ mask,
              const float* __restrict__ soft,
              const __hip_bfloat162* __restrict__ ntb,
              const __hip_bfloat16* __restrict__ table,
              const float* __restrict__ atom_tab,
              const float* __restrict__ nW1, const float* __restrict__ nb1,
              const float* __restrict__ ng,
              const float* __restrict__ nW2, const float* __restrict__ nb2,
              float* __restrict__ out)
{
    __shared__ K1S sm;
    const int t    = threadIdx.x;
    const int lane = t & 63;
    const int wv   = t >> 6;
    const int bi0  = blockIdx.x * 4;       // first global row of this block
    const int b    = bi0 >> 9;             // batch (4 rows never straddle b)

    // ---- wave-private ballot compaction: wave wv owns row bi0+wv ----
    const int ig      = bi0 + wv;          // global row index
    const int iloc    = ig & 511;          // i within batch
    const int rowbase = ig * Nn;
    const unsigned long long below = (1ull << lane) - 1ull;

    // hoisted embedding row (consumed only in the epilogue)
    const float2 embv = ((const float2*)&atom_tab[atoms[ig] * Dn])[lane];

    int cnt = 0;
    #pragma unroll
    for (int c = 0; c < 8; ++c) {
        const int j = c * 64 + lane;
        const float dist = rel[rowbase + j];
        const int   adjv = adj[rowbase + j];
        const int   mk   = mask[b * Nn + j];
        const float w = (adjv != 0 && mk != 0 && j != iloc) ? soft[rowbase + j] : 0.0f;
        int e = (int)(dist * (float)TT + 0.5f);
        e = min(max(e, 0), TT);
        const bool act = (w != 0.0f);
        const unsigned long long bm = __ballot(act);
        const int pre = __popcll(bm & below);
        if (act) sm.u.ent[wv][cnt + pre] =
            make_float2(w, __int_as_float(e | (atoms[b * Nn + j] << 16)));
        cnt += (int)__popcll(bm);
    }
    const int padded = (cnt + 7) & ~7;
    if (lane < padded - cnt)
        sm.u.ent[wv][cnt + lane] = make_float2(0.0f, __int_as_float(0));
    // NO block barrier: ent is written and read by the same wave only;
    // compiler-inserted lgkmcnt ordering is sufficient (R15-validated).

    // ---- contraction: s strides entries, lane covers 4 d ----
    const int s  = lane >> 5;
    const int dl = lane & 31;
    const int d0 = dl * 4;
    float a0 = 0.f, a1 = 0.f, a2 = 0.f, a3 = 0.f;
    #pragma unroll 8
    for (int n = s; n < padded; n += 2) {
        const float2 E  = sm.u.ent[wv][n];
        const float w   = E.x;
        const int  meta = __float_as_int(E.y);
        const int  e    = meta & 0xFFFF;
        const int  at   = meta >> 16;
        const __hip_bfloat162* tp = (const __hip_bfloat162*)&table[e * Dn + d0];
        const __hip_bfloat162 tva = tp[0], tvb = tp[1];
        const __hip_bfloat162* np = &ntb[at * 64 + dl * 2];   // global gather
        const __hip_bfloat162 nva = np[0], nvb = np[1];
        const float2 ta = __bfloat1622float2(tva);
        const float2 tb = __bfloat1622float2(tvb);
        const float2 na = __bfloat1622float2(nva);
        const float2 nb = __bfloat1622float2(nvb);
        a0 += (w * na.x) * ta.x;
        a1 += (w * na.y) * ta.y;
        a2 += (w * nb.x) * tb.x;
        a3 += (w * nb.y) * tb.y;
    }
    // cross-s reduction: lanes {dl, dl+32} hold partials of the same 4 d's.
    a0 += __shfl_xor(a0, 32);
    a1 += __shfl_xor(a1, 32);
    a2 += __shfl_xor(a2, 32);
    a3 += __shfl_xor(a3, 32);
    __syncthreads();    // B1: all ent reads done (union flip to epi is safe)

    // ---- stage xs = [emb | nf] (wave-owned row, nf straight from regs) ----
    ((float2*)&sm.u.epi.xs[wv][0])[lane] = embv;
    if (lane < 32)
        *(float4*)&sm.u.epi.xs[wv][Dn + d0] = make_float4(a0, a1, a2, a3);
    __syncthreads();    // B2

    const int og = t & 31;       // outputs 4*og .. 4*og+3
    const int ch = t >> 5;       // c-chunk 0..7

    // GEMV1: c-chunk of 32, weights reused across 4 rows
    {
        float acc[4][4];
        #pragma unroll
        for (int r = 0; r < 4; ++r)
            #pragma unroll
            for (int q = 0; q < 4; ++q) acc[r][q] = 0.f;
        const int c0 = ch * 32;
        #pragma unroll 8
        for (int c = 0; c < 32; ++c) {
            const float4 wv4 = *(const float4*)&nW1[(c0 + c) * Dn + og * 4];
            #pragma unroll
            for (int r = 0; r < 4; ++r) {
                const float xv = sm.u.epi.xs[r][c0 + c];
                acc[r][0] += xv * wv4.x; acc[r][1] += xv * wv4.y;
                acc[r][2] += xv * wv4.z; acc[r][3] += xv * wv4.w;
            }
        }
        #pragma unroll
        for (int r = 0; r < 4; ++r)
            *(float4*)&sm.u.epi.pp[ch][r][og * 4] =
                make_float4(acc[r][0], acc[r][1], acc[r][2], acc[r][3]);
    }
    __syncthreads();    // B3

    // fused bias + chunk-reduce + LN stats + silu: wave wv owns row wv
    {
        float lo = nb1[lane], hi = nb1[lane + 64];
        #pragma unroll
        for (int cc = 0; cc < 8; ++cc) {
            lo += sm.u.epi.pp[cc][wv][lane];
            hi += sm.u.epi.pp[cc][wv][lane + 64];
        }
        float s1 = lo + hi, s2 = lo * lo + hi * hi;
        #pragma unroll
        for (int m = 1; m < 64; m <<= 1) { s1 += __shfl_xor(s1, m); s2 += __shfl_xor(s2, m); }
        const float mean = s1 * (1.0f / 128.0f);
        const float var  = s2 * (1.0f / 128.0f) - mean * mean;
        const float rs   = rsqrtf(var + 1e-5f);
        sm.u.epi.x2[wv][lane]      = silu_f((lo - mean) * rs * ng[lane]);
        sm.u.epi.x2[wv][lane + 64] = silu_f((hi - mean) * rs * ng[lane + 64]);
    }
    __syncthreads();    // B4

    // GEMV2: c-chunk of 16
    {
        float acc[4][4];
        #pragma unroll
        for (int r = 0; r < 4; ++r)
            #pragma unroll
            for (int q = 0; q < 4; ++q) acc[r][q] = 0.f;
        const int c0 = ch * 16;
        #pragma unroll
        for (int c = 0; c < 16; ++c) {
            const float4 wv4 = *(const float4*)&nW2[(c0 + c) * Dn + og * 4];
            #pragma unroll
            for (int r = 0; r < 4; ++r) {
                const float xv = sm.u.epi.x2[r][c0 + c];
                acc[r][0] += xv * wv4.x; acc[r][1] += xv * wv4.y;
                acc[r][2] += xv * wv4.z; acc[r][3] += xv * wv4.w;
            }
        }
        #pragma unroll
        for (int r = 0; r < 4; ++r)
            *(float4*)&sm.u.epi.pp[ch][r][og * 4] =
                make_float4(acc[r][0], acc[r][1], acc[r][2], acc[r][3]);
    }
    __syncthreads();    // B5

    // final bias + chunk-reduce + store: wave wv owns row wv
    {
        float lo = nb2[lane], hi = nb2[lane + 64];
        #pragma unroll
        for (int cc = 0; cc < 8; ++cc) {
            lo += sm.u.epi.pp[cc][wv][lane];
            hi += sm.u.epi.pp[cc][wv][lane + 64];
        }
        out[(bi0 + wv) * Dn + lane]      = lo;
        out[(bi0 + wv) * Dn + lane + 64] = hi;
    }
}

// ---------------------------------------------------------------------------
extern "C" void kernel_launch(void* const* d_in, const int* in_sizes, int n_in,
                              void* d_out, int out_size, void* d_ws, size_t ws_size,
                              hipStream_t stream)
{
    (void)in_sizes; (void)n_in; (void)out_size; (void)ws_size;

    const int*   atoms = (const int*)d_in[0];
    const float* rel   = (const float*)d_in[1];
    const int*   adj   = (const int*)d_in[2];
    const int*   mask  = (const int*)d_in[3];
    const float* soft  = (const float*)d_in[4];
    const float* atab  = (const float*)d_in[5];
    const float* ntab  = (const float*)d_in[6];
    const float* rW1   = (const float*)d_in[7];
    const float* rb1   = (const float*)d_in[8];
    const float* rg1   = (const float*)d_in[9];
    const float* rW2   = (const float*)d_in[10];
    const float* rb2   = (const float*)d_in[11];
    const float* rg2   = (const float*)d_in[12];
    const float* rW3   = (const float*)d_in[13];
    const float* rb3   = (const float*)d_in[14];
    const float* nW1   = (const float*)d_in[15];
    const float* nb1   = (const float*)d_in[16];
    const float* ng    = (const float*)d_in[17];
    const float* nW2   = (const float*)d_in[18];
    const float* nb2   = (const float*)d_in[19];

    __hip_bfloat16*  table   = (__hip_bfloat16*)d_ws;                       // ~1 MB
    __hip_bfloat162* ntab_bf = (__hip_bfloat162*)((char*)d_ws + NTAB_BF_OFF); // 25.6 KB
    float* out = (float*)d_out;

    hipLaunchKernelGGL(k0_build_table, dim3(K0B), dim3(256), 0, stream,
                       rW1, rb1, rg1, rW2, rb2, rg2, rW3, rb3,
                       ntab, ntab_bf, table);
    hipLaunchKernelGGL(k1_fused, dim3(Bn * Nn / 4), dim3(256), 0, stream,
                       atoms, rel, adj, mask, soft, ntab_bf, table,
                       atab, nW1, nb1, ng, nW2, nb2, out);
}

// Round 5
// 135.934 us; speedup vs baseline: 1.0311x; 1.0311x over previous
//
#include <hip/hip_runtime.h>
#include <hip/hip_bf16.h>
#include <math.h>

#define Bn 4
#define Nn 512
#define Dn 128
#define Hn 64
#define TT 4096                  // table resolution (nearest-neighbor lookup)
#define EPB 8
#define K0B ((TT + 1 + EPB - 1) / EPB)
#define NTAB_BF_OFF (1 << 21)    // byte offset of bf16 ntab copy in workspace

__device__ __forceinline__ float silu_f(float x) {
    return x * (1.0f / (1.0f + __expf(-x)));
}

// ---------------------------------------------------------------------------
// k0: tabulate radial MLP G(x): scalar -> R^128 at x = e/TT.
// R17 = R15 form (LDS h-buf broadcast GEMVs, wave-private so no inner
// barriers) + 25 of the 513 blocks convert ntab fp32 -> bf16 into the
// workspace (bit-identical __float2bfloat16; k1 stages it as a raw copy).
// ---------------------------------------------------------------------------
struct K0S {
    float rW2s[Hn][Hn];
    float rW3s[Hn][Dn];
    float rW1s[Hn], rb1s[Hn], rg1s[Hn], rb2s[Hn], rg2s[Hn];
    float rb3s[Dn];
    float h1buf[4][Hn];
    float h2buf[4][Hn];
};

__global__ __launch_bounds__(256)
void k0_build_table(const float* __restrict__ rW1, const float* __restrict__ rb1,
                    const float* __restrict__ rg1,
                    const float* __restrict__ rW2, const float* __restrict__ rb2,
                    const float* __restrict__ rg2,
                    const float* __restrict__ rW3, const float* __restrict__ rb3,
                    const float* __restrict__ ntab,
                    __hip_bfloat162* __restrict__ ntab_bf,
                    __hip_bfloat16* __restrict__ table)
{
    __shared__ K0S sm;
    const int t  = threadIdx.x;
    const int k  = t & 63;
    const int wv = t >> 6;

    // bf16 ntab precompute: 100*128 floats = 6400 float2 = 25 blocks x 256 thr
    if (blockIdx.x < 25) {
        const int idx = blockIdx.x * 256 + t;
        const float2 fv = ((const float2*)ntab)[idx];
        ntab_bf[idx] = __hip_bfloat162(__float2bfloat16(fv.x), __float2bfloat16(fv.y));
    }

    #pragma unroll
    for (int idx = t; idx < Hn * Hn; idx += 256)
        sm.rW2s[idx >> 6][idx & 63] = rW2[idx];
    #pragma unroll
    for (int idx = t; idx < Hn * Dn; idx += 256)
        sm.rW3s[idx >> 7][idx & 127] = rW3[idx];
    if (t < Hn) {
        sm.rW1s[t] = rW1[t];
        sm.rb1s[t] = rb1[t];
        sm.rg1s[t] = rg1[t];
        sm.rb2s[t] = rb2[t];
        sm.rg2s[t] = rg2[t];
    }
    if (t < Dn) sm.rb3s[t] = rb3[t];
    __syncthreads();                      // only barrier in the kernel

    const float w1v = sm.rW1s[k], b1v = sm.rb1s[k], g1v = sm.rg1s[k];
    const float b2v = sm.rb2s[k], g2v = sm.rg2s[k];

    for (int r = 0; r < EPB / 4; ++r) {
        const int e = blockIdx.x * EPB + r * 4 + wv;
        const float x = (float)e * (1.0f / (float)TT);

        float h = silu_f(x * w1v + b1v);
        float s1 = h, s2 = h * h;
        #pragma unroll
        for (int m = 1; m < 64; m <<= 1) { s1 += __shfl_xor(s1, m); s2 += __shfl_xor(s2, m); }
        float mean = s1 * (1.0f / 64.0f);
        float var  = s2 * (1.0f / 64.0f) - mean * mean;
        float rs   = rsqrtf(var + 1e-5f);
        sm.h1buf[wv][k] = (h - mean) * rs * g1v;
        // wave-private buffer: same-wave DS ordering (lgkmcnt) suffices.

        float p = 0.f;
        #pragma unroll 8
        for (int kk = 0; kk < Hn; ++kk)
            p += sm.h1buf[wv][kk] * sm.rW2s[kk][k];
        float h2 = silu_f(p + b2v);
        s1 = h2; s2 = h2 * h2;
        #pragma unroll
        for (int m = 1; m < 64; m <<= 1) { s1 += __shfl_xor(s1, m); s2 += __shfl_xor(s2, m); }
        mean = s1 * (1.0f / 64.0f);
        var  = s2 * (1.0f / 64.0f) - mean * mean;
        rs   = rsqrtf(var + 1e-5f);
        sm.h2buf[wv][k] = (h2 - mean) * rs * g2v;

        #pragma unroll
        for (int dd = 0; dd < 2; ++dd) {
            const int d = dd * 64 + k;
            float f = sm.rb3s[d];
            #pragma unroll 8
            for (int kk = 0; kk < Hn; ++kk)
                f += sm.h2buf[wv][kk] * sm.rW3s[kk][d];
            if (e <= TT) table[e * Dn + d] = __float2bfloat16(f);
        }
    }
}

// ---------------------------------------------------------------------------
// k1: fully fused.  Block = 4 rows (512 blocks); wave = one full row.
// R17 = R15 (best, 135.4 us) with ONE change:
//   - ntab staging is now a raw bf16 copy (float4 loads of k0's precomputed
//     ntab_bf): 25.6 KB instead of 51.2 KB fp32 + 12800 cvts per block, on
//     the serial path before B1.  Contraction keeps the R15-proven LDS
//     gathers (R16's global-gather form cost +5 us: 2 dependent VMEM/iter
//     in the latency-bound inner loop -- reverted).
//   - everything else bit-identical to R15.
// ---------------------------------------------------------------------------
struct alignas(16) K1S {
    __hip_bfloat162 ntabS[100 * 64];       // 25.6 KB
    union {
        float2 ent[4][512];                // wave-private entry lists (16 KB)
        struct {
            float xs[4][256];              // 4 KB  [emb | nf] per row
            float pp[8][4][128];           // 16 KB GEMV partials [ch][row][out]
            float x2[4][128];              // 2 KB  post-LN/silu
        } epi;                             // 22 KB
    } u;
};

__global__ __launch_bounds__(256)
void k1_fused(const int* __restrict__ atoms, const float* __restrict__ rel,
              const int* __restrict__ adj, const int* __restrict__ mask,
              const float* __restrict__ soft,
              const __hip_bfloat162* __restrict__ ntb,
              const __hip_bfloat16* __restrict__ table,
              const float* __restrict__ atom_tab,
              const float* __restrict__ nW1, const float* __restrict__ nb1,
              const float* __restrict__ ng,
              const float* __restrict__ nW2, const float* __restrict__ nb2,
              float* __restrict__ out)
{
    __shared__ K1S sm;
    const int t    = threadIdx.x;
    const int lane = t & 63;
    const int wv   = t >> 6;
    const int bi0  = blockIdx.x * 4;       // first global row of this block
    const int b    = bi0 >> 9;             // batch (4 rows never straddle b)

    // ---- stage ntab -> LDS (raw bf16 copy, 1600 x float4) ----
    for (int idx = t; idx < 1600; idx += 256)
        ((float4*)sm.ntabS)[idx] = ((const float4*)ntb)[idx];

    // ---- wave-private ballot compaction: wave wv owns row bi0+wv ----
    const int ig      = bi0 + wv;          // global row index
    const int iloc    = ig & 511;          // i within batch
    const int rowbase = ig * Nn;
    const unsigned long long below = (1ull << lane) - 1ull;

    // hoisted embedding row (consumed only in the epilogue)
    const float2 embv = ((const float2*)&atom_tab[atoms[ig] * Dn])[lane];

    int cnt = 0;
    #pragma unroll
    for (int c = 0; c < 8; ++c) {
        const int j = c * 64 + lane;
        const float dist = rel[rowbase + j];
        const int   adjv = adj[rowbase + j];
        const int   mk   = mask[b * Nn + j];
        const float w = (adjv != 0 && mk != 0 && j != iloc) ? soft[rowbase + j] : 0.0f;
        int e = (int)(dist * (float)TT + 0.5f);
        e = min(max(e, 0), TT);
        const bool act = (w != 0.0f);
        const unsigned long long bm = __ballot(act);
        const int pre = __popcll(bm & below);
        if (act) sm.u.ent[wv][cnt + pre] =
            make_float2(w, __int_as_float(e | (atoms[b * Nn + j] << 16)));
        cnt += (int)__popcll(bm);
    }
    const int padded = (cnt + 7) & ~7;
    if (lane < padded - cnt)
        sm.u.ent[wv][cnt + lane] = make_float2(0.0f, __int_as_float(0));
    __syncthreads();    // B1: ntabS + ent visible

    // ---- contraction (R15-proven): s strides entries, lane covers 4 d ----
    const int s  = lane >> 5;
    const int dl = lane & 31;
    const int d0 = dl * 4;
    float a0 = 0.f, a1 = 0.f, a2 = 0.f, a3 = 0.f;
    #pragma unroll 8
    for (int n = s; n < padded; n += 2) {
        const float2 E  = sm.u.ent[wv][n];
        const float w   = E.x;
        const int  meta = __float_as_int(E.y);
        const int  e    = meta & 0xFFFF;
        const int  at   = meta >> 16;
        const __hip_bfloat162* tp = (const __hip_bfloat162*)&table[e * Dn + d0];
        const __hip_bfloat162 tva = tp[0], tvb = tp[1];
        const __hip_bfloat162 nva = sm.ntabS[at * 64 + dl * 2];
        const __hip_bfloat162 nvb = sm.ntabS[at * 64 + dl * 2 + 1];
        const float2 ta = __bfloat1622float2(tva);
        const float2 tb = __bfloat1622float2(tvb);
        const float2 na = __bfloat1622float2(nva);
        const float2 nb = __bfloat1622float2(nvb);
        a0 += (w * na.x) * ta.x;
        a1 += (w * na.y) * ta.y;
        a2 += (w * nb.x) * tb.x;
        a3 += (w * nb.y) * tb.y;
    }
    // cross-s reduction: lanes {dl, dl+32} hold partials of the same 4 d's.
    a0 += __shfl_xor(a0, 32);
    a1 += __shfl_xor(a1, 32);
    a2 += __shfl_xor(a2, 32);
    a3 += __shfl_xor(a3, 32);
    __syncthreads();    // B2: all ent reads done (union flip to epi is safe)

    // ---- stage xs = [emb | nf] (wave-owned row, nf straight from regs) ----
    ((float2*)&sm.u.epi.xs[wv][0])[lane] = embv;
    if (lane < 32)
        *(float4*)&sm.u.epi.xs[wv][Dn + d0] = make_float4(a0, a1, a2, a3);
    __syncthreads();    // B3

    const int og = t & 31;       // outputs 4*og .. 4*og+3
    const int ch = t >> 5;       // c-chunk 0..7

    // GEMV1: c-chunk of 32, weights reused across 4 rows
    {
        float acc[4][4];
        #pragma unroll
        for (int r = 0; r < 4; ++r)
            #pragma unroll
            for (int q = 0; q < 4; ++q) acc[r][q] = 0.f;
        const int c0 = ch * 32;
        #pragma unroll 8
        for (int c = 0; c < 32; ++c) {
            const float4 wv4 = *(const float4*)&nW1[(c0 + c) * Dn + og * 4];
            #pragma unroll
            for (int r = 0; r < 4; ++r) {
                const float xv = sm.u.epi.xs[r][c0 + c];
                acc[r][0] += xv * wv4.x; acc[r][1] += xv * wv4.y;
                acc[r][2] += xv * wv4.z; acc[r][3] += xv * wv4.w;
            }
        }
        #pragma unroll
        for (int r = 0; r < 4; ++r)
            *(float4*)&sm.u.epi.pp[ch][r][og * 4] =
                make_float4(acc[r][0], acc[r][1], acc[r][2], acc[r][3]);
    }
    __syncthreads();    // B4

    // fused bias + chunk-reduce + LN stats + silu: wave wv owns row wv
    {
        float lo = nb1[lane], hi = nb1[lane + 64];
        #pragma unroll
        for (int cc = 0; cc < 8; ++cc) {
            lo += sm.u.epi.pp[cc][wv][lane];
            hi += sm.u.epi.pp[cc][wv][lane + 64];
        }
        float s1 = lo + hi, s2 = lo * lo + hi * hi;
        #pragma unroll
        for (int m = 1; m < 64; m <<= 1) { s1 += __shfl_xor(s1, m); s2 += __shfl_xor(s2, m); }
        const float mean = s1 * (1.0f / 128.0f);
        const float var  = s2 * (1.0f / 128.0f) - mean * mean;
        const float rs   = rsqrtf(var + 1e-5f);
        sm.u.epi.x2[wv][lane]      = silu_f((lo - mean) * rs * ng[lane]);
        sm.u.epi.x2[wv][lane + 64] = silu_f((hi - mean) * rs * ng[lane + 64]);
    }
    __syncthreads();    // B5

    // GEMV2: c-chunk of 16
    {
        float acc[4][4];
        #pragma unroll
        for (int r = 0; r < 4; ++r)
            #pragma unroll
            for (int q = 0; q < 4; ++q) acc[r][q] = 0.f;
        const int c0 = ch * 16;
        #pragma unroll
        for (int c = 0; c < 16; ++c) {
            const float4 wv4 = *(const float4*)&nW2[(c0 + c) * Dn + og * 4];
            #pragma unroll
            for (int r = 0; r < 4; ++r) {
                const float xv = sm.u.epi.x2[r][c0 + c];
                acc[r][0] += xv * wv4.x; acc[r][1] += xv * wv4.y;
                acc[r][2] += xv * wv4.z; acc[r][3] += xv * wv4.w;
            }
        }
        #pragma unroll
        for (int r = 0; r < 4; ++r)
            *(float4*)&sm.u.epi.pp[ch][r][og * 4] =
                make_float4(acc[r][0], acc[r][1], acc[r][2], acc[r][3]);
    }
    __syncthreads();    // B6

    // final bias + chunk-reduce + store: wave wv owns row wv
    {
        float lo = nb2[lane], hi = nb2[lane + 64];
        #pragma unroll
        for (int cc = 0; cc < 8; ++cc) {
            lo += sm.u.epi.pp[cc][wv][lane];
            hi += sm.u.epi.pp[cc][wv][lane + 64];
        }
        out[(bi0 + wv) * Dn + lane]      = lo;
        out[(bi0 + wv) * Dn + lane + 64] = hi;
    }
}

// ---------------------------------------------------------------------------
extern "C" void kernel_launch(void* const* d_in, const int* in_sizes, int n_in,
                              void* d_out, int out_size, void* d_ws, size_t ws_size,
                              hipStream_t stream)
{
    (void)in_sizes; (void)n_in; (void)out_size; (void)ws_size;

    const int*   atoms = (const int*)d_in[0];
    const float* rel   = (const float*)d_in[1];
    const int*   adj   = (const int*)d_in[2];
    const int*   mask  = (const int*)d_in[3];
    const float* soft  = (const float*)d_in[4];
    const float* atab  = (const float*)d_in[5];
    const float* ntab  = (const float*)d_in[6];
    const float* rW1   = (const float*)d_in[7];
    const float* rb1   = (const float*)d_in[8];
    const float* rg1   = (const float*)d_in[9];
    const float* rW2   = (const float*)d_in[10];
    const float* rb2   = (const float*)d_in[11];
    const float* rg2   = (const float*)d_in[12];
    const float* rW3   = (const float*)d_in[13];
    const float* rb3   = (const float*)d_in[14];
    const float* nW1   = (const float*)d_in[15];
    const float* nb1   = (const float*)d_in[16];
    const float* ng    = (const float*)d_in[17];
    const float* nW2   = (const float*)d_in[18];
    const float* nb2   = (const float*)d_in[19];

    __hip_bfloat16*  table   = (__hip_bfloat16*)d_ws;                         // ~1 MB
    __hip_bfloat162* ntab_bf = (__hip_bfloat162*)((char*)d_ws + NTAB_BF_OFF); // 25.6 KB
    float* out = (float*)d_out;

    hipLaunchKernelGGL(k0_build_table, dim3(K0B), dim3(256), 0, stream,
                       rW1, rb1, rg1, rW2, rb2, rg2, rW3, rb3,
                       ntab, ntab_bf, table);
    hipLaunchKernelGGL(k1_fused, dim3(Bn * Nn / 4), dim3(256), 0, stream,
                       atoms, rel, adj, mask, soft, ntab_bf, table,
                       atab, nW1, nb1, ng, nW2, nb2, out);
}